// Round 6
// baseline (152.636 us; speedup 1.0000x reference)
//
#include <hip/hip_runtime.h>

#define ALPHA 0.2f

typedef __attribute__((ext_vector_type(8))) short short8;
typedef __attribute__((ext_vector_type(8))) unsigned short ushort8;
typedef __attribute__((ext_vector_type(16))) float f32x16;

__device__ __forceinline__ float bf2f(unsigned short u) {
    return __uint_as_float(((unsigned int)u) << 16);
}
__device__ __forceinline__ unsigned short f2bf(float f) {
    unsigned int x = __float_as_uint(f);
    unsigned int r = (x + 0x7fffu + ((x >> 16) & 1u)) >> 16;   // RNE
    return (unsigned short)r;
}

// ---------------------------------------------------------------------------
// Kernel 0: dtype detection. flags[0]=1 -> floats fp32. flags[1]=1 -> edges int64.
// ---------------------------------------------------------------------------
__global__ __launch_bounds__(256) void detect_types(const unsigned int* __restrict__ xw,
                                                    const int* __restrict__ ei32,
                                                    int* __restrict__ flags) {
    __shared__ int cnt[2];
    if (threadIdx.x == 0) { cnt[0] = 0; cnt[1] = 0; }
    __syncthreads();
    int c0 = 0, c1 = 0;
    int t = threadIdx.x;
    for (int i = 0; i < 8; i++) {
        int k = t * 8 + i;
        unsigned int u = xw[k];
        unsigned int e = (u >> 7) & 0xffu;
        if (e >= 0x58u && e <= 0x90u) c0++;
        if (ei32[2 * k + 1] != 0) c1++;
    }
    atomicAdd(&cnt[0], c0);
    atomicAdd(&cnt[1], c1);
    __syncthreads();
    if (threadIdx.x == 0) {
        flags[0] = (cnt[0] < 1200) ? 1 : 0;
        flags[1] = (cnt[1] < 1000) ? 1 : 0;
    }
}

// ---------------------------------------------------------------------------
// Kernel 1: split fp32 -> bf16 hi/lo planes. x planes [N][C]; W planes
// TRANSPOSED to [H][F][C] (so wt rows are k-contiguous for direct B-frag loads).
// ---------------------------------------------------------------------------
__global__ __launch_bounds__(256) void split_bf16(const void* __restrict__ x_raw,
                                                  const void* __restrict__ W_raw,
                                                  unsigned short* __restrict__ x_hi,
                                                  unsigned short* __restrict__ x_lo,
                                                  unsigned short* __restrict__ wt_hi,
                                                  unsigned short* __restrict__ wt_lo,
                                                  const int* __restrict__ flags) {
    int is32 = flags[0];
    int bid = blockIdx.x, tid = threadIdx.x;
    if (bid < 1024) {
        size_t base = ((size_t)bid * 256 + tid) * 8;
        ushort8 h8, l8;
        if (is32) {
            const float* xf = (const float*)x_raw;
            float4 v0 = *(const float4*)(xf + base);
            float4 v1 = *(const float4*)(xf + base + 4);
            float v[8] = {v0.x, v0.y, v0.z, v0.w, v1.x, v1.y, v1.z, v1.w};
#pragma unroll
            for (int j = 0; j < 8; j++) {
                unsigned short hi = f2bf(v[j]);
                h8[j] = hi;
                l8[j] = f2bf(v[j] - bf2f(hi));
            }
        } else {
            const ushort8* xb = (const ushort8*)x_raw;
            h8 = xb[base / 8];
            l8 = (ushort8)0;
        }
        *(ushort8*)(x_hi + base) = h8;
        *(ushort8*)(x_lo + base) = l8;
    } else {
        size_t u = ((size_t)(bid - 1024) * 256 + tid) * 8;
#pragma unroll
        for (int j = 0; j < 8; j++) {
            size_t e = u + j;
            int head = (int)(e >> 15);
            int c = (int)((e >> 6) & 511);
            int f = (int)(e & 63);
            unsigned short hi, lo;
            if (is32) {
                float v = ((const float*)W_raw)[e];
                hi = f2bf(v);
                lo = f2bf(v - bf2f(hi));
            } else {
                hi = ((const unsigned short*)W_raw)[e];
                lo = 0;
            }
            size_t o = (size_t)head * 32768 + (size_t)f * 512 + c;
            wt_hi[o] = hi;
            wt_lo[o] = lo;
        }
    }
}

// ---------------------------------------------------------------------------
// Kernel 2: adjacency bitmask (dedup like the reference boolean adj).
// ---------------------------------------------------------------------------
__global__ __launch_bounds__(256) void build_adj(const int* __restrict__ ei, int E, int N,
                                                 unsigned long long* __restrict__ adj,
                                                 const int* __restrict__ flags) {
    int is64 = flags[1];
    int t = blockIdx.x * blockDim.x + threadIdx.x;
    int words = N >> 6;
    if (t < E) {
        int r = is64 ? ei[2 * t]       : ei[t];
        int c = is64 ? ei[2 * (E + t)] : ei[E + t];
        atomicOr(&adj[(size_t)r * words + (c >> 6)], 1ull << (c & 63));
    } else if (t < E + N) {
        int i = t - E;
        atomicOr(&adj[(size_t)i * words + (i >> 6)], 1ull << (i & 63));
    }
}

// ---------------------------------------------------------------------------
// Kernel 3: MFMA GEMM (bf16x3) as one M=4096,N=512 GEMM.
// Block 64x64 (by = head), 4 waves, each one mfma_32x32x16 tile:
//   wave w: rows (w&1)*32, cols (w>>1)*32.
// A staged in double-buffered LDS (only A!); B-frags loaded DIRECTLY from
// global (wt rows k-contiguous -> 16B loads, L1/L2-resident).
// One barrier per K-iter; depth-2 A-prefetch, depth-1 B-prefetch.
// ---------------------------------------------------------------------------
#define LRA 40
__global__ __launch_bounds__(256) void gemm_mfma(const unsigned short* __restrict__ xh,
                                                 const unsigned short* __restrict__ xl,
                                                 const unsigned short* __restrict__ wth,
                                                 const unsigned short* __restrict__ wtl,
                                                 const void* __restrict__ a_raw,
                                                 unsigned short* __restrict__ h2b,
                                                 float* __restrict__ s_src2,
                                                 float* __restrict__ s_dst2,
                                                 const int* __restrict__ flags) {
    __shared__ unsigned short sA[2][64 * LRA];

    int bx = blockIdx.x, by = blockIdx.y;
    int tid = threadIdx.x;
    int w = tid >> 6, lane = tid & 63;
    int half = lane >> 5, n32 = lane & 31;
    int r0 = (w & 1) * 32, c0 = (w >> 1) * 32;
    int row0 = bx * 64;

    const unsigned short* Ap[3] = {xh, xl, xh};
    const unsigned short* Bp[3] = {wth, wth, wtl};

    int srow = tid >> 2, skc = tid & 3;
    size_t baseA = (size_t)(row0 + srow) * 512 + skc * 8;
    size_t baseB = (size_t)(by * 64 + c0 + n32) * 512 + half * 8;

    int ldsw = srow * LRA + skc * 8;
    int ldsr = (r0 + n32) * LRA + half * 8;

    f32x16 acc = {0.f, 0.f, 0.f, 0.f, 0.f, 0.f, 0.f, 0.f,
                  0.f, 0.f, 0.f, 0.f, 0.f, 0.f, 0.f, 0.f};

    // preamble: A chunks 0,1 in regs; B frags for chunk 0 in regs; stage A chunk 0.
    ushort8 ra0 = *(const ushort8*)(Ap[0] + baseA);
    ushort8 ra1 = *(const ushort8*)(Ap[0] + baseA + 32);
    short8 b0c = *(const short8*)(Bp[0] + baseB);
    short8 b1c = *(const short8*)(Bp[0] + baseB + 16);
    *(ushort8*)&sA[0][ldsw] = ra0;
    __syncthreads();

    for (int i = 0; i < 48; i++) {
        int cur = i & 1;
        if (i + 2 < 48) {                              // A prefetch, depth 2
            int c = i + 2;
            const unsigned short* p = Ap[c >> 4];
            size_t ko = (size_t)(c & 15) * 32;
            ushort8 r = *(const ushort8*)(p + baseA + ko);
            if (cur == 0) ra0 = r; else ra1 = r;
        }
        short8 b0n, b1n;
        bool haveN = (i + 1 < 48);
        if (haveN) {                                   // B prefetch, depth 1
            int c = i + 1;
            const unsigned short* p = Bp[c >> 4];
            size_t ko = (size_t)(c & 15) * 32;
            b0n = *(const short8*)(p + baseB + ko);
            b1n = *(const short8*)(p + baseB + ko + 16);
        }
        short8 a0 = *(const short8*)&sA[cur][ldsr];
        short8 a1 = *(const short8*)&sA[cur][ldsr + 16];
        acc = __builtin_amdgcn_mfma_f32_32x32x16_bf16(a0, b0c, acc, 0, 0, 0);
        acc = __builtin_amdgcn_mfma_f32_32x32x16_bf16(a1, b1c, acc, 0, 0, 0);
        if (haveN) {
            b0c = b0n; b1c = b1n;
            *(ushort8*)&sA[cur ^ 1][ldsw] = (cur == 0) ? ra1 : ra0;
        }
        __syncthreads();
    }

    // --- epilogue. D layout (32x32): col = lane&31, row = (reg&3)+8*(reg>>2)+4*half
#pragma unroll
    for (int reg = 0; reg < 16; reg++) {
        int rloc = (reg & 3) + 8 * (reg >> 2) + 4 * half;
        int r = row0 + r0 + rloc;
        h2b[(size_t)r * 512 + by * 64 + c0 + n32] = f2bf(acc[reg]);
    }

    float as, ad;
    if (flags[0]) {
        const float* af = (const float*)a_raw + by * 128;
        as = af[c0 + n32]; ad = af[64 + c0 + n32];
    } else {
        const unsigned short* ab = (const unsigned short*)a_raw + by * 128;
        as = bf2f(ab[c0 + n32]); ad = bf2f(ab[64 + c0 + n32]);
    }
    float s1v[16], s2v[16];
#pragma unroll
    for (int reg = 0; reg < 16; reg++) {
        float s1 = acc[reg] * as, s2 = acc[reg] * ad;
#pragma unroll
        for (int d = 1; d < 32; d <<= 1) { s1 += __shfl_xor(s1, d); s2 += __shfl_xor(s2, d); }
        s1v[reg] = s1; s2v[reg] = s2;
    }
    float* sS = (float*)&sA[0][0];            // [64 rows][2]
    __syncthreads();
    if (c0 == 0 && n32 == 0) {
#pragma unroll
        for (int reg = 0; reg < 16; reg++) {
            int rloc = r0 + (reg & 3) + 8 * (reg >> 2) + 4 * half;
            sS[rloc * 2 + 0] = s1v[reg];
            sS[rloc * 2 + 1] = s2v[reg];
        }
    }
    __syncthreads();
    if (c0 == 32 && n32 == 0) {
#pragma unroll
        for (int reg = 0; reg < 16; reg++) {
            int rloc = r0 + (reg & 3) + 8 * (reg >> 2) + 4 * half;
            int r = row0 + rloc;
            s_src2[(size_t)r * 8 + by] = sS[rloc * 2 + 0] + s1v[reg];
            s_dst2[(size_t)r * 8 + by] = sS[rloc * 2 + 1] + s2v[reg];
        }
    }
}

// ---------------------------------------------------------------------------
// Kernel 4: attention + aggregation + row softmax. ONE WAVE PER NODE.
// Lane owns features lane*8..lane*8+7 (head = lane>>3): exactly one exp per
// lane per neighbor. Adjacency row held in registers, walked via ballot+shfl.
// No LDS, no block barriers.
// ---------------------------------------------------------------------------
__global__ __launch_bounds__(256) void attn_out(const unsigned short* __restrict__ h2b,
                                                const float* __restrict__ s_src2,
                                                const float* __restrict__ s_dst2,
                                                const unsigned long long* __restrict__ adj,
                                                void* __restrict__ out_raw,
                                                const int* __restrict__ flags) {
    int wid = threadIdx.x >> 6, lane = threadIdx.x & 63;
    int i = blockIdx.x * 4 + wid;
    int myhead = lane >> 3;

    unsigned long long myword = adj[(size_t)i * 64 + lane];
    unsigned int wlo = (unsigned int)myword, whi = (unsigned int)(myword >> 32);
    unsigned long long nz = __ballot(myword != 0ull);
    float ssrc = s_src2[(size_t)i * 8 + myhead];

    // pass 1: per-head max of s_dst over neighbors
    float mx = -1e30f;
    unsigned long long nzw = nz;
    while (nzw) {
        int t = __ffsll(nzw) - 1; nzw &= nzw - 1;
        unsigned long long word = ((unsigned long long)(unsigned int)__shfl((int)whi, t) << 32)
                                  | (unsigned int)__shfl((int)wlo, t);
        int base = t << 6;
        while (word) {
            int b = __ffsll(word) - 1; word &= word - 1;
            mx = fmaxf(mx, s_dst2[(size_t)(base + b) * 8 + myhead]);
        }
    }
    float pre = ssrc + mx;
    float maxe = pre > 0.f ? pre : ALPHA * pre;

    // pass 2: weights + aggregate (one exp/lane/neighbor, 1KB coalesced h2b row)
    float den = 0.f;
    float ax[8] = {0.f, 0.f, 0.f, 0.f, 0.f, 0.f, 0.f, 0.f};
    nzw = nz;
    while (nzw) {
        int t = __ffsll(nzw) - 1; nzw &= nzw - 1;
        unsigned long long word = ((unsigned long long)(unsigned int)__shfl((int)whi, t) << 32)
                                  | (unsigned int)__shfl((int)wlo, t);
        int base = t << 6;
        while (word) {
            int b = __ffsll(word) - 1; word &= word - 1;
            int j = base + b;
            float e = ssrc + s_dst2[(size_t)j * 8 + myhead];
            e = e > 0.f ? e : ALPHA * e;
            float wgt = __expf(e - maxe);
            den += wgt;
            ushort8 u = *(const ushort8*)(h2b + (size_t)j * 512 + lane * 8);
#pragma unroll
            for (int k = 0; k < 8; k++) ax[k] += wgt * bf2f(u[k]);
        }
    }
    float rden = 1.f / den;

    // wave-wide softmax over 512 features (8 per lane)
    float o[8];
    float m = -1e30f;
#pragma unroll
    for (int k = 0; k < 8; k++) { o[k] = ax[k] * rden; m = fmaxf(m, o[k]); }
#pragma unroll
    for (int d = 1; d < 64; d <<= 1) m = fmaxf(m, __shfl_xor(m, d));
    float s = 0.f;
#pragma unroll
    for (int k = 0; k < 8; k++) { o[k] = __expf(o[k] - m); s += o[k]; }
#pragma unroll
    for (int d = 1; d < 64; d <<= 1) s += __shfl_xor(s, d);
    float rs = 1.f / s;

    if (flags[0]) {
        float* outf = (float*)out_raw + (size_t)i * 512 + lane * 8;
        *(float4*)outf       = make_float4(o[0] * rs, o[1] * rs, o[2] * rs, o[3] * rs);
        *(float4*)(outf + 4) = make_float4(o[4] * rs, o[5] * rs, o[6] * rs, o[7] * rs);
    } else {
        ushort8 pk;
#pragma unroll
        for (int k = 0; k < 8; k++) pk[k] = f2bf(o[k] * rs);
        *(ushort8*)((unsigned short*)out_raw + (size_t)i * 512 + lane * 8) = pk;
    }
}

// ---------------------------------------------------------------------------
extern "C" void kernel_launch(void* const* d_in, const int* in_sizes, int n_in,
                              void* d_out, int out_size, void* d_ws, size_t ws_size,
                              hipStream_t stream) {
    const int N = 4096, H = 8;
    const int E = in_sizes[1] / 2;

    const void* x = d_in[0];
    const int*  ei = (const int*)d_in[1];
    const void* W = d_in[2];
    const void* a = d_in[3];

    char* ws = (char*)d_ws;
    unsigned short* h2b = (unsigned short*)ws;                           // 4 MB
    float* s_src2 = (float*)(ws + (size_t)4 * 1024 * 1024);              // 128 KB
    float* s_dst2 = s_src2 + (size_t)N * H;                              // 128 KB
    unsigned long long* adj = (unsigned long long*)(ws + (size_t)5 * 1024 * 1024); // 2 MB
    int* flags = (int*)(ws + (size_t)7 * 1024 * 1024 + 512 * 1024);
    unsigned short* x_hi  = (unsigned short*)(ws + (size_t)8 * 1024 * 1024);       // 4 MB
    unsigned short* x_lo  = (unsigned short*)(ws + (size_t)12 * 1024 * 1024);      // 4 MB
    unsigned short* wt_hi = (unsigned short*)(ws + (size_t)16 * 1024 * 1024);      // 512 KB
    unsigned short* wt_lo = (unsigned short*)(ws + (size_t)16 * 1024 * 1024 + 512 * 1024);

    hipMemsetAsync(adj, 0, (size_t)N * (N / 8), stream);

    detect_types<<<1, 256, 0, stream>>>((const unsigned int*)x, ei, flags);
    split_bf16<<<1152, 256, 0, stream>>>(x, W, x_hi, x_lo, wt_hi, wt_lo, flags);
    build_adj<<<(E + N + 255) / 256, 256, 0, stream>>>(ei, E, N, adj, flags);
    gemm_mfma<<<dim3(N / 64, H), 256, 0, stream>>>(x_hi, x_lo, wt_hi, wt_lo, a,
                                                   h2b, s_src2, s_dst2, flags);
    attn_out<<<N / 4, 256, 0, stream>>>(h2b, s_src2, s_dst2, adj, d_out, flags);
}

// Round 7
// 130.225 us; speedup vs baseline: 1.1721x; 1.1721x over previous
//
#include <hip/hip_runtime.h>

#define ALPHA 0.2f

typedef __attribute__((ext_vector_type(8))) short short8;
typedef __attribute__((ext_vector_type(8))) unsigned short ushort8;
typedef __attribute__((ext_vector_type(4))) float f32x4;

__device__ __forceinline__ float bf2f(unsigned short u) {
    return __uint_as_float(((unsigned int)u) << 16);
}
__device__ __forceinline__ unsigned short f2bf(float f) {
    unsigned int x = __float_as_uint(f);
    unsigned int r = (x + 0x7fffu + ((x >> 16) & 1u)) >> 16;   // RNE
    return (unsigned short)r;
}

// ---------------------------------------------------------------------------
// Kernel 0: dtype detection. flags[0]=1 -> floats fp32. flags[1]=1 -> edges int64.
// ---------------------------------------------------------------------------
__global__ __launch_bounds__(256) void detect_types(const unsigned int* __restrict__ xw,
                                                    const int* __restrict__ ei32,
                                                    int* __restrict__ flags) {
    __shared__ int cnt[2];
    if (threadIdx.x == 0) { cnt[0] = 0; cnt[1] = 0; }
    __syncthreads();
    int c0 = 0, c1 = 0;
    int t = threadIdx.x;
    for (int i = 0; i < 8; i++) {
        int k = t * 8 + i;
        unsigned int u = xw[k];
        unsigned int e = (u >> 7) & 0xffu;
        if (e >= 0x58u && e <= 0x90u) c0++;
        if (ei32[2 * k + 1] != 0) c1++;
    }
    atomicAdd(&cnt[0], c0);
    atomicAdd(&cnt[1], c1);
    __syncthreads();
    if (threadIdx.x == 0) {
        flags[0] = (cnt[0] < 1200) ? 1 : 0;
        flags[1] = (cnt[1] < 1000) ? 1 : 0;
    }
}

// ---------------------------------------------------------------------------
// Kernel 1: split fp32 -> bf16 hi/lo planes. x planes [N][C]; W planes
// TRANSPOSED to [H][F][C].
// ---------------------------------------------------------------------------
__global__ __launch_bounds__(256) void split_bf16(const void* __restrict__ x_raw,
                                                  const void* __restrict__ W_raw,
                                                  unsigned short* __restrict__ x_hi,
                                                  unsigned short* __restrict__ x_lo,
                                                  unsigned short* __restrict__ wt_hi,
                                                  unsigned short* __restrict__ wt_lo,
                                                  const int* __restrict__ flags) {
    int is32 = flags[0];
    int bid = blockIdx.x, tid = threadIdx.x;
    if (bid < 1024) {
        size_t base = ((size_t)bid * 256 + tid) * 8;
        ushort8 h8, l8;
        if (is32) {
            const float* xf = (const float*)x_raw;
            float4 v0 = *(const float4*)(xf + base);
            float4 v1 = *(const float4*)(xf + base + 4);
            float v[8] = {v0.x, v0.y, v0.z, v0.w, v1.x, v1.y, v1.z, v1.w};
#pragma unroll
            for (int j = 0; j < 8; j++) {
                unsigned short hi = f2bf(v[j]);
                h8[j] = hi;
                l8[j] = f2bf(v[j] - bf2f(hi));
            }
        } else {
            const ushort8* xb = (const ushort8*)x_raw;
            h8 = xb[base / 8];
            l8 = (ushort8)0;
        }
        *(ushort8*)(x_hi + base) = h8;
        *(ushort8*)(x_lo + base) = l8;
    } else {
        size_t u = ((size_t)(bid - 1024) * 256 + tid) * 8;
#pragma unroll
        for (int j = 0; j < 8; j++) {
            size_t e = u + j;
            int head = (int)(e >> 15);
            int c = (int)((e >> 6) & 511);
            int f = (int)(e & 63);
            unsigned short hi, lo;
            if (is32) {
                float v = ((const float*)W_raw)[e];
                hi = f2bf(v);
                lo = f2bf(v - bf2f(hi));
            } else {
                hi = ((const unsigned short*)W_raw)[e];
                lo = 0;
            }
            size_t o = (size_t)head * 32768 + (size_t)f * 512 + c;
            wt_hi[o] = hi;
            wt_lo[o] = lo;
        }
    }
}

// ---------------------------------------------------------------------------
// Kernel 2: adjacency bitmask (dedup like the reference boolean adj).
// ---------------------------------------------------------------------------
__global__ __launch_bounds__(256) void build_adj(const int* __restrict__ ei, int E, int N,
                                                 unsigned long long* __restrict__ adj,
                                                 const int* __restrict__ flags) {
    int is64 = flags[1];
    int t = blockIdx.x * blockDim.x + threadIdx.x;
    int words = N >> 6;
    if (t < E) {
        int r = is64 ? ei[2 * t]       : ei[t];
        int c = is64 ? ei[2 * (E + t)] : ei[E + t];
        atomicOr(&adj[(size_t)r * words + (c >> 6)], 1ull << (c & 63));
    } else if (t < E + N) {
        int i = t - E;
        atomicOr(&adj[(size_t)i * words + (i >> 6)], 1ull << (i & 63));
    }
}

// ---------------------------------------------------------------------------
// Kernel 3: MFMA GEMM (bf16x3), 16x16x32, depth-2 prefetch (r4 structure,
// best-measured). Outputs h2b (bf16 [N][512]) + fp32 s_src2/s_dst2.
// ---------------------------------------------------------------------------
#define LROW 40
__global__ __launch_bounds__(256) void gemm_mfma(const unsigned short* __restrict__ xh,
                                                 const unsigned short* __restrict__ xl,
                                                 const unsigned short* __restrict__ wth,
                                                 const unsigned short* __restrict__ wtl,
                                                 const void* __restrict__ a_raw,
                                                 unsigned short* __restrict__ h2b,
                                                 float* __restrict__ s_src2,
                                                 float* __restrict__ s_dst2,
                                                 const int* __restrict__ flags) {
    __shared__ unsigned short sA[64 * LROW];
    __shared__ unsigned short sB[64 * LROW];

    int head = blockIdx.y;
    int row0 = blockIdx.x * 64;
    int tid = threadIdx.x;
    int w = tid >> 6, lane = tid & 63;
    int m = lane & 15, quad = lane >> 4;
    int sr = tid >> 2, sc = tid & 3;

    const unsigned short* Ap[3] = {xh, xl, xh};
    const unsigned short* Bp[3] = {wth, wth, wtl};
    size_t baseA = (size_t)(row0 + sr) * 512 + sc * 8;
    size_t baseB = (size_t)head * 32768 + (size_t)sr * 512 + sc * 8;

    f32x4 acc[4] = {f32x4{0.f, 0.f, 0.f, 0.f}, f32x4{0.f, 0.f, 0.f, 0.f},
                    f32x4{0.f, 0.f, 0.f, 0.f}, f32x4{0.f, 0.f, 0.f, 0.f}};

    int ldsw = sr * LROW + sc * 8;
    int ldsA = (w * 16 + m) * LROW + quad * 8;

    ushort8 ra0 = *(const ushort8*)(Ap[0] + baseA);
    ushort8 rb0 = *(const ushort8*)(Bp[0] + baseB);
    ushort8 ra1 = *(const ushort8*)(Ap[0] + baseA + 32);
    ushort8 rb1 = *(const ushort8*)(Bp[0] + baseB + 32);

    for (int i = 0; i < 48; i += 2) {
        __syncthreads();
        *(ushort8*)&sA[ldsw] = ra0;
        *(ushort8*)&sB[ldsw] = rb0;
        __syncthreads();
        {
            int inx = i + 2;
            if (inx < 48) {
                int pn = inx >> 4, kn = (inx & 15) * 32;
                ra0 = *(const ushort8*)(Ap[pn] + baseA + kn);
                rb0 = *(const ushort8*)(Bp[pn] + baseB + kn);
            }
        }
        {
            short8 af = *(const short8*)&sA[ldsA];
#pragma unroll
            for (int t = 0; t < 4; t++) {
                short8 bf = *(const short8*)&sB[(t * 16 + m) * LROW + quad * 8];
                acc[t] = __builtin_amdgcn_mfma_f32_16x16x32_bf16(af, bf, acc[t], 0, 0, 0);
            }
        }
        __syncthreads();
        *(ushort8*)&sA[ldsw] = ra1;
        *(ushort8*)&sB[ldsw] = rb1;
        __syncthreads();
        {
            int inx = i + 3;
            if (inx < 48) {
                int pn = inx >> 4, kn = (inx & 15) * 32;
                ra1 = *(const ushort8*)(Ap[pn] + baseA + kn);
                rb1 = *(const ushort8*)(Bp[pn] + baseB + kn);
            }
        }
        {
            short8 af = *(const short8*)&sA[ldsA];
#pragma unroll
            for (int t = 0; t < 4; t++) {
                short8 bf = *(const short8*)&sB[(t * 16 + m) * LROW + quad * 8];
                acc[t] = __builtin_amdgcn_mfma_f32_16x16x32_bf16(af, bf, acc[t], 0, 0, 0);
            }
        }
    }

    // epilogue: h2b bf16; D layout: col = lane&15, row = quad*4+reg
#pragma unroll
    for (int t = 0; t < 4; t++)
#pragma unroll
        for (int reg = 0; reg < 4; reg++) {
            int r = row0 + w * 16 + quad * 4 + reg;
            h2b[(size_t)r * 512 + head * 64 + t * 16 + m] = f2bf(acc[t][reg]);
        }

    float as[4], ad[4];
    if (flags[0]) {
        const float* af32 = (const float*)a_raw + head * 128;
#pragma unroll
        for (int t = 0; t < 4; t++) {
            as[t] = af32[t * 16 + m];
            ad[t] = af32[64 + t * 16 + m];
        }
    } else {
        const unsigned short* ab = (const unsigned short*)a_raw + head * 128;
#pragma unroll
        for (int t = 0; t < 4; t++) {
            as[t] = bf2f(ab[t * 16 + m]);
            ad[t] = bf2f(ab[64 + t * 16 + m]);
        }
    }
#pragma unroll
    for (int reg = 0; reg < 4; reg++) {
        float s1 = as[0] * acc[0][reg] + as[1] * acc[1][reg] + as[2] * acc[2][reg] + as[3] * acc[3][reg];
        float s2 = ad[0] * acc[0][reg] + ad[1] * acc[1][reg] + ad[2] * acc[2][reg] + ad[3] * acc[3][reg];
#pragma unroll
        for (int d = 1; d < 16; d <<= 1) {
            s1 += __shfl_xor(s1, d);
            s2 += __shfl_xor(s2, d);
        }
        if (m == 0) {
            int r = row0 + w * 16 + quad * 4 + reg;
            s_src2[(size_t)r * 8 + head] = s1;
            s_dst2[(size_t)r * 8 + head] = s2;
        }
    }
}

// ---------------------------------------------------------------------------
// Kernel 4: attention + aggregation + row softmax. Block per node i
// (r3 structure, best-measured) with bf16 h2b gathers (1KB/neighbor).
// Weight pass: thread t handles (neighbor t>>3, head t&7) -> 8 exps/neighbor.
// Acc pass: thread owns head tid>>5, 2 features; weight via LDS broadcast.
// ---------------------------------------------------------------------------
__global__ __launch_bounds__(256) void attn_out(const unsigned short* __restrict__ h2b,
                                                const float* __restrict__ s_src2,
                                                const float* __restrict__ s_dst2,
                                                const unsigned long long* __restrict__ adj,
                                                void* __restrict__ out_raw,
                                                const int* __restrict__ flags) {
    __shared__ unsigned short nbrs[4096];
    __shared__ float w_lds[256 * 8];
    __shared__ float sss[8], smax[8], sden[8];
    __shared__ float sredw[4][8];
    __shared__ float sr[8];
    __shared__ int s_cnt;

    int i = blockIdx.x;
    int tid = threadIdx.x;
    int lane = tid & 63, wid = tid >> 6;

    // Phase 1: enumerate neighbors (wave 0); stage s_src row.
    if (tid < 64) {
        unsigned long long word = adj[(size_t)i * 64 + tid];
        int cnt = __popcll(word);
        int incl = cnt;
#pragma unroll
        for (int d = 1; d < 64; d <<= 1) {
            int v = __shfl_up(incl, d);
            if (tid >= d) incl += v;
        }
        int off = incl - cnt;
        unsigned long long w = word;
        int base = tid * 64;
        while (w) {
            int b = __ffsll((unsigned long long)w) - 1;
            nbrs[off++] = (unsigned short)(base + b);
            w &= w - 1;
        }
        if (tid == 63) s_cnt = incl;
    }
    if (tid >= 64 && tid < 72) sss[tid - 64] = s_src2[(size_t)i * 8 + (tid - 64)];
    __syncthreads();
    int cnt = s_cnt;

    // Phase 2: per-head max of s_dst over neighbors.
    int hw = tid & 7;
    float mp = -1e30f;
    for (int t = tid; t < cnt * 8; t += 256)
        mp = fmaxf(mp, s_dst2[(size_t)nbrs[t >> 3] * 8 + hw]);
    mp = fmaxf(mp, __shfl_down(mp, 32));
    mp = fmaxf(mp, __shfl_down(mp, 16));
    mp = fmaxf(mp, __shfl_down(mp, 8));
    if (lane < 8) sredw[wid][lane] = mp;
    __syncthreads();
    if (tid < 8) {
        float m = fmaxf(fmaxf(sredw[0][tid], sredw[1][tid]), fmaxf(sredw[2][tid], sredw[3][tid]));
        float pre = sss[tid] + m;
        smax[tid] = pre > 0.f ? pre : ALPHA * pre;
    }
    __syncthreads();

    // Phase 3: chunked weights + bf16 gather accumulation.
    int hh = tid >> 5;
    float ssrc_w = sss[hw], maxe_w = smax[hw];
    float den = 0.f, ax = 0.f, ay = 0.f;
    for (int c0 = 0; c0 < cnt; c0 += 256) {
        int csz = min(256, cnt - c0);
        __syncthreads();
        for (int t = tid; t < csz * 8; t += 256) {
            int j = nbrs[c0 + (t >> 3)];
            float e = ssrc_w + s_dst2[(size_t)j * 8 + hw];
            e = e > 0.f ? e : ALPHA * e;
            float w = __expf(e - maxe_w);
            w_lds[t] = w;
            den += w;
        }
        __syncthreads();
#pragma unroll 2
        for (int jj = 0; jj < csz; jj++) {
            int j = nbrs[c0 + jj];
            unsigned int u = *(const unsigned int*)(h2b + (size_t)j * 512 + tid * 2);
            float w = w_lds[jj * 8 + hh];
            ax += w * bf2f((unsigned short)(u & 0xffffu));
            ay += w * bf2f((unsigned short)(u >> 16));
        }
    }

    // Phase 4: reduce den per head.
    den += __shfl_down(den, 32);
    den += __shfl_down(den, 16);
    den += __shfl_down(den, 8);
    if (lane < 8) sredw[wid][lane] = den;
    __syncthreads();
    if (tid < 8) sden[tid] = sredw[0][tid] + sredw[1][tid] + sredw[2][tid] + sredw[3][tid];
    __syncthreads();
    float dtot = sden[hh];
    float o0 = ax / dtot, o1 = ay / dtot;

    // Phase 5: fused row softmax over 512 (2 per thread).
    float m2 = fmaxf(o0, o1);
#pragma unroll
    for (int d = 32; d; d >>= 1) m2 = fmaxf(m2, __shfl_down(m2, d));
    if (lane == 0) sr[wid] = m2;
    __syncthreads();
    float m = fmaxf(fmaxf(sr[0], sr[1]), fmaxf(sr[2], sr[3]));
    float e0 = __expf(o0 - m), e1 = __expf(o1 - m);
    float s = e0 + e1;
#pragma unroll
    for (int d = 32; d; d >>= 1) s += __shfl_down(s, d);
    __syncthreads();
    if (lane == 0) sr[wid + 4] = s;
    __syncthreads();
    s = sr[4] + sr[5] + sr[6] + sr[7];

    if (flags[0]) {
        float2* out = (float2*)out_raw;
        out[(size_t)i * 256 + tid] = make_float2(e0 / s, e1 / s);
    } else {
        unsigned int* out = (unsigned int*)out_raw;
        out[(size_t)i * 256 + tid] = (unsigned int)f2bf(e0 / s) | ((unsigned int)f2bf(e1 / s) << 16);
    }
}

// ---------------------------------------------------------------------------
extern "C" void kernel_launch(void* const* d_in, const int* in_sizes, int n_in,
                              void* d_out, int out_size, void* d_ws, size_t ws_size,
                              hipStream_t stream) {
    const int N = 4096, H = 8;
    const int E = in_sizes[1] / 2;

    const void* x = d_in[0];
    const int*  ei = (const int*)d_in[1];
    const void* W = d_in[2];
    const void* a = d_in[3];

    char* ws = (char*)d_ws;
    unsigned short* h2b = (unsigned short*)ws;                           // 4 MB
    float* s_src2 = (float*)(ws + (size_t)4 * 1024 * 1024);              // 128 KB
    float* s_dst2 = s_src2 + (size_t)N * H;                              // 128 KB
    unsigned long long* adj = (unsigned long long*)(ws + (size_t)5 * 1024 * 1024); // 2 MB
    int* flags = (int*)(ws + (size_t)7 * 1024 * 1024 + 512 * 1024);
    unsigned short* x_hi  = (unsigned short*)(ws + (size_t)8 * 1024 * 1024);       // 4 MB
    unsigned short* x_lo  = (unsigned short*)(ws + (size_t)12 * 1024 * 1024);      // 4 MB
    unsigned short* wt_hi = (unsigned short*)(ws + (size_t)16 * 1024 * 1024);      // 512 KB
    unsigned short* wt_lo = (unsigned short*)(ws + (size_t)16 * 1024 * 1024 + 512 * 1024);

    hipMemsetAsync(adj, 0, (size_t)N * (N / 8), stream);

    detect_types<<<1, 256, 0, stream>>>((const unsigned int*)x, ei, flags);
    split_bf16<<<1152, 256, 0, stream>>>(x, W, x_hi, x_lo, wt_hi, wt_lo, flags);
    build_adj<<<(E + N + 255) / 256, 256, 0, stream>>>(ei, E, N, adj, flags);
    gemm_mfma<<<dim3(N / 64, H), 256, 0, stream>>>(x_hi, x_lo, wt_hi, wt_lo, a,
                                                   h2b, s_src2, s_dst2, flags);
    attn_out<<<N, 256, 0, stream>>>(h2b, s_src2, s_dst2, adj, d_out, flags);
}

// Round 8
// 119.215 us; speedup vs baseline: 1.2803x; 1.0924x over previous
//
#include <hip/hip_runtime.h>

#define ALPHA 0.2f

typedef __attribute__((ext_vector_type(8))) short short8;
typedef __attribute__((ext_vector_type(8))) unsigned short ushort8;
typedef __attribute__((ext_vector_type(4))) float f32x4;

__device__ __forceinline__ float bf2f(unsigned short u) {
    return __uint_as_float(((unsigned int)u) << 16);
}
__device__ __forceinline__ unsigned short f2bf(float f) {
    unsigned int x = __float_as_uint(f);
    unsigned int r = (x + 0x7fffu + ((x >> 16) & 1u)) >> 16;   // RNE
    return (unsigned short)r;
}

// Per-wave fp32-vs-bf16 detection: sample 64 words of x, check bf16-exponent
// plausibility of the low u16. bf16 data -> ~64/64 plausible; fp32 -> ~14/64.
__device__ __forceinline__ int detect_is32(const unsigned int* xw) {
    int lane = threadIdx.x & 63;
    unsigned int u = xw[lane];
    unsigned int e = (u >> 7) & 0xffu;
    unsigned long long b = __ballot(e >= 0x58u && e <= 0x90u);
    return (__popcll(b) < 40) ? 1 : 0;
}

// ---------------------------------------------------------------------------
// Kernel 1: split fp32 -> bf16 hi/lo planes. x planes [N][C]; W planes
// TRANSPOSED to [H][F][C]. Self-detects dtype; block 0 publishes flags[0].
// ---------------------------------------------------------------------------
__global__ __launch_bounds__(256) void split_bf16(const void* __restrict__ x_raw,
                                                  const void* __restrict__ W_raw,
                                                  unsigned short* __restrict__ x_hi,
                                                  unsigned short* __restrict__ x_lo,
                                                  unsigned short* __restrict__ wt_hi,
                                                  unsigned short* __restrict__ wt_lo,
                                                  int* __restrict__ flags) {
    int bid = blockIdx.x, tid = threadIdx.x;
    int is32 = detect_is32((const unsigned int*)x_raw);
    if (bid == 0 && tid == 0) flags[0] = is32;

    if (bid < 1024) {
        size_t base = ((size_t)bid * 256 + tid) * 8;
        ushort8 h8, l8;
        if (is32) {
            const float* xf = (const float*)x_raw;
            float4 v0 = *(const float4*)(xf + base);
            float4 v1 = *(const float4*)(xf + base + 4);
            float v[8] = {v0.x, v0.y, v0.z, v0.w, v1.x, v1.y, v1.z, v1.w};
#pragma unroll
            for (int j = 0; j < 8; j++) {
                unsigned short hi = f2bf(v[j]);
                h8[j] = hi;
                l8[j] = f2bf(v[j] - bf2f(hi));
            }
        } else {
            const ushort8* xb = (const ushort8*)x_raw;
            h8 = xb[base / 8];
            l8 = (ushort8)0;
        }
        *(ushort8*)(x_hi + base) = h8;
        *(ushort8*)(x_lo + base) = l8;
    } else {
        size_t u = ((size_t)(bid - 1024) * 256 + tid) * 8;
#pragma unroll
        for (int j = 0; j < 8; j++) {
            size_t e = u + j;
            int head = (int)(e >> 15);
            int c = (int)((e >> 6) & 511);
            int f = (int)(e & 63);
            unsigned short hi, lo;
            if (is32) {
                float v = ((const float*)W_raw)[e];
                hi = f2bf(v);
                lo = f2bf(v - bf2f(hi));
            } else {
                hi = ((const unsigned short*)W_raw)[e];
                lo = 0;
            }
            size_t o = (size_t)head * 32768 + (size_t)f * 512 + c;
            wt_hi[o] = hi;
            wt_lo[o] = lo;
        }
    }
}

// ---------------------------------------------------------------------------
// Kernel 2: adjacency bitmask (dedup like the reference boolean adj).
// Self-detects int64 vs int32 edge_index via per-wave ballot.
// ---------------------------------------------------------------------------
__global__ __launch_bounds__(256) void build_adj(const int* __restrict__ ei, int E, int N,
                                                 unsigned long long* __restrict__ adj) {
    int lane = threadIdx.x & 63;
    unsigned long long nz = __ballot(ei[2 * lane + 1] != 0);
    int is64 = (nz == 0ull) ? 1 : 0;      // int64 high halves are all zero

    int t = blockIdx.x * blockDim.x + threadIdx.x;
    int words = N >> 6;
    if (t < E) {
        int r = is64 ? ei[2 * t]       : ei[t];
        int c = is64 ? ei[2 * (E + t)] : ei[E + t];
        atomicOr(&adj[(size_t)r * words + (c >> 6)], 1ull << (c & 63));
    } else if (t < E + N) {
        int i = t - E;
        atomicOr(&adj[(size_t)i * words + (i >> 6)], 1ull << (i & 63));
    }
}

// ---------------------------------------------------------------------------
// Kernel 3: MFMA GEMM (bf16x3), BK=64, true LDS double-buffer:
// ONE barrier per K-iter (24 iters vs r7's 192 barriers), depth-2 global
// prefetch (loads issued a full phase before their ds_write).
// Block: 64 rows x 64 cols (one head), 4 waves x 4 tiles of 16x16x32.
// ---------------------------------------------------------------------------
#define LROW 72
__global__ __launch_bounds__(256) void gemm_mfma(const unsigned short* __restrict__ xh,
                                                 const unsigned short* __restrict__ xl,
                                                 const unsigned short* __restrict__ wth,
                                                 const unsigned short* __restrict__ wtl,
                                                 const void* __restrict__ a_raw,
                                                 unsigned short* __restrict__ h2b,
                                                 float* __restrict__ s_src2,
                                                 float* __restrict__ s_dst2,
                                                 const int* __restrict__ flags) {
    __shared__ unsigned short sA[2][64 * LROW];
    __shared__ unsigned short sB[2][64 * LROW];

    int head = blockIdx.y;
    int row0 = blockIdx.x * 64;
    int tid = threadIdx.x;
    int w = tid >> 6, lane = tid & 63;
    int m = lane & 15, quad = lane >> 4;
    int srow = tid >> 2, sc = tid & 3;

    const unsigned short* Ap[3] = {xh, xl, xh};
    const unsigned short* Bp[3] = {wth, wth, wtl};
    size_t baseA = (size_t)(row0 + srow) * 512 + sc * 8;
    size_t baseB = (size_t)head * 32768 + (size_t)srow * 512 + sc * 8;

    int ldsw  = srow * LROW + sc * 8;
    int ldsAr = (w * 16 + m) * LROW + quad * 8;

    f32x4 acc[4] = {f32x4{0.f, 0.f, 0.f, 0.f}, f32x4{0.f, 0.f, 0.f, 0.f},
                    f32x4{0.f, 0.f, 0.f, 0.f}, f32x4{0.f, 0.f, 0.f, 0.f}};

    // iter c (0..23): plane = c>>3, k-offset = (c&7)*64; chunks at +0 and +32.
#define LOADSET(Aa, Ab, Ba, Bb, c)                                         \
    {                                                                      \
        const unsigned short* pA = Ap[(c) >> 3];                           \
        const unsigned short* pB = Bp[(c) >> 3];                           \
        size_t ko = (size_t)((c) & 7) * 64;                                \
        Aa = *(const ushort8*)(pA + baseA + ko);                           \
        Ab = *(const ushort8*)(pA + baseA + ko + 32);                      \
        Ba = *(const ushort8*)(pB + baseB + ko);                           \
        Bb = *(const ushort8*)(pB + baseB + ko + 32);                      \
    }

#define WRITESET(buf, Aa, Ab, Ba, Bb)                                      \
    {                                                                      \
        *(ushort8*)&sA[buf][ldsw]      = Aa;                               \
        *(ushort8*)&sA[buf][ldsw + 32] = Ab;                               \
        *(ushort8*)&sB[buf][ldsw]      = Ba;                               \
        *(ushort8*)&sB[buf][ldsw + 32] = Bb;                               \
    }

#define COMPUTE(buf)                                                       \
    {                                                                      \
        short8 af0 = *(const short8*)&sA[buf][ldsAr];                      \
        short8 af1 = *(const short8*)&sA[buf][ldsAr + 32];                 \
        _Pragma("unroll")                                                  \
        for (int t = 0; t < 4; t++) {                                      \
            int bo = (t * 16 + m) * LROW + quad * 8;                       \
            short8 bf0 = *(const short8*)&sB[buf][bo];                     \
            short8 bf1 = *(const short8*)&sB[buf][bo + 32];                \
            acc[t] = __builtin_amdgcn_mfma_f32_16x16x32_bf16(af0, bf0, acc[t], 0, 0, 0); \
            acc[t] = __builtin_amdgcn_mfma_f32_16x16x32_bf16(af1, bf1, acc[t], 0, 0, 0); \
        }                                                                  \
    }

    ushort8 a0a, a0b, b0a, b0b;    // even set
    ushort8 a1a, a1b, b1a, b1b;    // odd set

    LOADSET(a0a, a0b, b0a, b0b, 0)
    LOADSET(a1a, a1b, b1a, b1b, 1)
    WRITESET(0, a0a, a0b, b0a, b0b)
    __syncthreads();

    for (int i = 0; i < 24; i += 2) {
        // EVEN: compute buf0 (iter i); prefetch iter i+2 into even set;
        //       stage odd set (iter i+1) -> buf1.
        if (i + 2 < 24) LOADSET(a0a, a0b, b0a, b0b, i + 2)
        COMPUTE(0)
        WRITESET(1, a1a, a1b, b1a, b1b)
        __syncthreads();
        // ODD: compute buf1 (iter i+1); prefetch iter i+3 into odd set;
        //      stage even set (iter i+2) -> buf0.
        if (i + 3 < 24) LOADSET(a1a, a1b, b1a, b1b, i + 3)
        COMPUTE(1)
        if (i + 2 < 24) WRITESET(0, a0a, a0b, b0a, b0b)
        __syncthreads();
    }

    // epilogue: h2b bf16; D layout: col = lane&15, row = quad*4+reg
#pragma unroll
    for (int t = 0; t < 4; t++)
#pragma unroll
        for (int reg = 0; reg < 4; reg++) {
            int r = row0 + w * 16 + quad * 4 + reg;
            h2b[(size_t)r * 512 + head * 64 + t * 16 + m] = f2bf(acc[t][reg]);
        }

    float as[4], ad[4];
    if (flags[0]) {
        const float* af32 = (const float*)a_raw + head * 128;
#pragma unroll
        for (int t = 0; t < 4; t++) {
            as[t] = af32[t * 16 + m];
            ad[t] = af32[64 + t * 16 + m];
        }
    } else {
        const unsigned short* ab = (const unsigned short*)a_raw + head * 128;
#pragma unroll
        for (int t = 0; t < 4; t++) {
            as[t] = bf2f(ab[t * 16 + m]);
            ad[t] = bf2f(ab[64 + t * 16 + m]);
        }
    }
#pragma unroll
    for (int reg = 0; reg < 4; reg++) {
        float s1 = as[0] * acc[0][reg] + as[1] * acc[1][reg] + as[2] * acc[2][reg] + as[3] * acc[3][reg];
        float s2 = ad[0] * acc[0][reg] + ad[1] * acc[1][reg] + ad[2] * acc[2][reg] + ad[3] * acc[3][reg];
#pragma unroll
        for (int d = 1; d < 16; d <<= 1) {
            s1 += __shfl_xor(s1, d);
            s2 += __shfl_xor(s2, d);
        }
        if (m == 0) {
            int r = row0 + w * 16 + quad * 4 + reg;
            s_src2[(size_t)r * 8 + head] = s1;
            s_dst2[(size_t)r * 8 + head] = s2;
        }
    }
}

// ---------------------------------------------------------------------------
// Kernel 4: attention + aggregation + row softmax. Block per node i
// (unchanged from r7 — control variable this round).
// ---------------------------------------------------------------------------
__global__ __launch_bounds__(256) void attn_out(const unsigned short* __restrict__ h2b,
                                                const float* __restrict__ s_src2,
                                                const float* __restrict__ s_dst2,
                                                const unsigned long long* __restrict__ adj,
                                                void* __restrict__ out_raw,
                                                const int* __restrict__ flags) {
    __shared__ unsigned short nbrs[4096];
    __shared__ float w_lds[256 * 8];
    __shared__ float sss[8], smax[8], sden[8];
    __shared__ float sredw[4][8];
    __shared__ float sr[8];
    __shared__ int s_cnt;

    int i = blockIdx.x;
    int tid = threadIdx.x;
    int lane = tid & 63, wid = tid >> 6;

    if (tid < 64) {
        unsigned long long word = adj[(size_t)i * 64 + tid];
        int cnt = __popcll(word);
        int incl = cnt;
#pragma unroll
        for (int d = 1; d < 64; d <<= 1) {
            int v = __shfl_up(incl, d);
            if (tid >= d) incl += v;
        }
        int off = incl - cnt;
        unsigned long long w = word;
        int base = tid * 64;
        while (w) {
            int b = __ffsll((unsigned long long)w) - 1;
            nbrs[off++] = (unsigned short)(base + b);
            w &= w - 1;
        }
        if (tid == 63) s_cnt = incl;
    }
    if (tid >= 64 && tid < 72) sss[tid - 64] = s_src2[(size_t)i * 8 + (tid - 64)];
    __syncthreads();
    int cnt = s_cnt;

    int hw = tid & 7;
    float mp = -1e30f;
    for (int t = tid; t < cnt * 8; t += 256)
        mp = fmaxf(mp, s_dst2[(size_t)nbrs[t >> 3] * 8 + hw]);
    mp = fmaxf(mp, __shfl_down(mp, 32));
    mp = fmaxf(mp, __shfl_down(mp, 16));
    mp = fmaxf(mp, __shfl_down(mp, 8));
    if (lane < 8) sredw[wid][lane] = mp;
    __syncthreads();
    if (tid < 8) {
        float m = fmaxf(fmaxf(sredw[0][tid], sredw[1][tid]), fmaxf(sredw[2][tid], sredw[3][tid]));
        float pre = sss[tid] + m;
        smax[tid] = pre > 0.f ? pre : ALPHA * pre;
    }
    __syncthreads();

    int hh = tid >> 5;
    float ssrc_w = sss[hw], maxe_w = smax[hw];
    float den = 0.f, ax = 0.f, ay = 0.f;
    for (int c0 = 0; c0 < cnt; c0 += 256) {
        int csz = min(256, cnt - c0);
        __syncthreads();
        for (int t = tid; t < csz * 8; t += 256) {
            int j = nbrs[c0 + (t >> 3)];
            float e = ssrc_w + s_dst2[(size_t)j * 8 + hw];
            e = e > 0.f ? e : ALPHA * e;
            float w = __expf(e - maxe_w);
            w_lds[t] = w;
            den += w;
        }
        __syncthreads();
#pragma unroll 2
        for (int jj = 0; jj < csz; jj++) {
            int j = nbrs[c0 + jj];
            unsigned int u = *(const unsigned int*)(h2b + (size_t)j * 512 + tid * 2);
            float w = w_lds[jj * 8 + hh];
            ax += w * bf2f((unsigned short)(u & 0xffffu));
            ay += w * bf2f((unsigned short)(u >> 16));
        }
    }

    den += __shfl_down(den, 32);
    den += __shfl_down(den, 16);
    den += __shfl_down(den, 8);
    if (lane < 8) sredw[wid][lane] = den;
    __syncthreads();
    if (tid < 8) sden[tid] = sredw[0][tid] + sredw[1][tid] + sredw[2][tid] + sredw[3][tid];
    __syncthreads();
    float dtot = sden[hh];
    float o0 = ax / dtot, o1 = ay / dtot;

    float m2 = fmaxf(o0, o1);
#pragma unroll
    for (int d = 32; d; d >>= 1) m2 = fmaxf(m2, __shfl_down(m2, d));
    if (lane == 0) sr[wid] = m2;
    __syncthreads();
    float m = fmaxf(fmaxf(sr[0], sr[1]), fmaxf(sr[2], sr[3]));
    float e0 = __expf(o0 - m), e1 = __expf(o1 - m);
    float s = e0 + e1;
#pragma unroll
    for (int d = 32; d; d >>= 1) s += __shfl_down(s, d);
    __syncthreads();
    if (lane == 0) sr[wid + 4] = s;
    __syncthreads();
    s = sr[4] + sr[5] + sr[6] + sr[7];

    if (flags[0]) {
        float2* out = (float2*)out_raw;
        out[(size_t)i * 256 + tid] = make_float2(e0 / s, e1 / s);
    } else {
        unsigned int* out = (unsigned int*)out_raw;
        out[(size_t)i * 256 + tid] = (unsigned int)f2bf(e0 / s) | ((unsigned int)f2bf(e1 / s) << 16);
    }
}

// ---------------------------------------------------------------------------
extern "C" void kernel_launch(void* const* d_in, const int* in_sizes, int n_in,
                              void* d_out, int out_size, void* d_ws, size_t ws_size,
                              hipStream_t stream) {
    const int N = 4096, H = 8;
    const int E = in_sizes[1] / 2;

    const void* x = d_in[0];
    const int*  ei = (const int*)d_in[1];
    const void* W = d_in[2];
    const void* a = d_in[3];

    char* ws = (char*)d_ws;
    unsigned short* h2b = (unsigned short*)ws;                           // 4 MB
    float* s_src2 = (float*)(ws + (size_t)4 * 1024 * 1024);              // 128 KB
    float* s_dst2 = s_src2 + (size_t)N * H;                              // 128 KB
    unsigned long long* adj = (unsigned long long*)(ws + (size_t)5 * 1024 * 1024); // 2 MB
    int* flags = (int*)(ws + (size_t)7 * 1024 * 1024 + 512 * 1024);
    unsigned short* x_hi  = (unsigned short*)(ws + (size_t)8 * 1024 * 1024);       // 4 MB
    unsigned short* x_lo  = (unsigned short*)(ws + (size_t)12 * 1024 * 1024);      // 4 MB
    unsigned short* wt_hi = (unsigned short*)(ws + (size_t)16 * 1024 * 1024);      // 512 KB
    unsigned short* wt_lo = (unsigned short*)(ws + (size_t)16 * 1024 * 1024 + 512 * 1024);

    hipMemsetAsync(adj, 0, (size_t)N * (N / 8), stream);

    split_bf16<<<1152, 256, 0, stream>>>(x, W, x_hi, x_lo, wt_hi, wt_lo, flags);
    build_adj<<<(E + N + 255) / 256, 256, 0, stream>>>(ei, E, N, adj);
    gemm_mfma<<<dim3(N / 64, H), 256, 0, stream>>>(x_hi, x_lo, wt_hi, wt_lo, a,
                                                   h2b, s_src2, s_dst2, flags);
    attn_out<<<N, 256, 0, stream>>>(h2b, s_src2, s_dst2, adj, d_out, flags);
}